// Round 5
// baseline (1123.460 us; speedup 1.0000x reference)
//
#include <hip/hip_runtime.h>

// Conv1dFFTInt8: B=16, CIN=128, COUT=128, L=4096, out_size==1.
// Identity: ifft(sum_l X[l]W[l])[0] = sum_n x[n] * w[(L-n) mod L]  (real inputs)
// => out[b,o] = bias[o] + sum_i sum_m w[o,i,m] * x[b,i,(L-m)&(L-1)]
// HBM-bound skinny dot: weight 256MB streamed exactly once; x 32MB L2/L3-resident.
//
// R5: split the memory streams onto different wait counters.
//  - x: staged ONCE per block into LDS (reversed), read via ds_read_b128
//    (lgkmcnt) -> never pollutes the vmcnt stream. ONE barrier per kernel.
//  - weight: the only vmcnt traffic. All 16 dwordx4 (16 KB/wave) issued
//    upfront, drained across 4 compute iters -> ~128 KB/CU in flight vs the
//    ~9.2 KB needed to saturate HBM (R4 had ~1 KB -> 690 GB/s, 8.6%).
// R4's failure: x(L2) and w(HBM) shared one in-order vmcnt chain; every wait
// on x drained the 900-cyc weight prefetch -> pure latency serialization.

constexpr int LEN   = 4096;
constexpr int CIN_  = 128;
constexpr int COUT_ = 128;
constexpr int BATCH = 16;
constexpr int KR    = 1024;   // k-range per block (quarter channel)

__global__ void init_out_kernel(const float* __restrict__ bias, float* __restrict__ out) {
    int t = blockIdx.x * 256 + threadIdx.x;
    if (t < BATCH * COUT_) out[t] = bias[t & (COUT_ - 1)];
}

// Grid 4096 = ot(8) x [ci(128) x kr(4)](512). Block 256 thr = 4 waves; wave
// owns 4 cout rows, acc[16][4] in VGPRs. Same-(ci,kr) blocks are 512 apart
// (512 % 8 == 0 -> same XCD) -> shared L2 for that x slice.
__global__ __launch_bounds__(256, 2)   // 256-VGPR budget; (256,3) spills acc!
void conv_dot_kernel(const float* __restrict__ x, const float* __restrict__ w,
                     float* __restrict__ out) {
    __shared__ float xs[BATCH * KR];   // 64 KB: xs[b][t] = x[b,ci,(4096-kbase-t)&4095]

    const int tid   = threadIdx.x;
    const int lane  = tid & 63;
    const int wv    = tid >> 6;
    const int bk    = blockIdx.x;      // 0..4095
    const int ot    = bk >> 9;         // 0..7
    const int r     = bk & 511;
    const int ci    = r >> 2;          // 0..127
    const int kbase = (r & 3) << 10;   // 0,1024,2048,3072
    const int obase = ot * 16 + wv * 4;

    const float* xci = x + (ci << 12);

    // ---- stage reversed x, once. Coalesced: consecutive tid -> descending n.
    {
        const int n0 = 4093 - kbase - (tid << 2);
        const bool wrap = (kbase == 0) && (tid == 0);   // k=0 -> n=0 wrap
#pragma unroll
        for (int b = 0; b < BATCH; ++b) {
            const float* xb = xci + (b << 19);   // b * CIN*LEN
            float4 v;
            if (wrap) { v.x = xb[4093]; v.y = xb[4094]; v.z = xb[4095]; v.w = xb[0]; }
            else       v = *(const float4*)(xb + n0);
            // reversed components: xs[t0+i] = x[n0+3-i]
            *(float4*)(xs + (b << 10) + (tid << 2)) = make_float4(v.w, v.z, v.y, v.x);
        }
    }
    __syncthreads();   // the ONLY barrier

    // ---- issue ALL weight loads upfront: 4 couts x 4 iters = 16 KB/wave in flight
    const float* wrowp[4];
#pragma unroll
    for (int j = 0; j < 4; ++j)
        wrowp[j] = w + (((obase + j) * CIN_ + ci) << 12) + kbase + (lane << 2);

    float4 wreg[4][4];   // [it][j]
#pragma unroll
    for (int it = 0; it < 4; ++it)
#pragma unroll
        for (int j = 0; j < 4; ++j)
            wreg[it][j] = *(const float4*)(wrowp[j] + (it << 8));

    float acc[BATCH][4];
#pragma unroll
    for (int b = 0; b < BATCH; ++b)
#pragma unroll
        for (int j = 0; j < 4; ++j) acc[b][j] = 0.f;

    // ---- compute: x from LDS (lgkmcnt), weight drains vmcnt(12/8/4/0)
#pragma unroll
    for (int it = 0; it < 4; ++it) {
        const float* xit = xs + (it << 8) + (lane << 2);
#pragma unroll
        for (int b = 0; b < BATCH; ++b) {
            const float4 xv = *(const float4*)(xit + (b << 10));  // ds_read_b128
#pragma unroll
            for (int j = 0; j < 4; ++j) {
                acc[b][j] += xv.x * wreg[it][j].x;
                acc[b][j] += xv.y * wreg[it][j].y;
                acc[b][j] += xv.z * wreg[it][j].z;
                acc[b][j] += xv.w * wreg[it][j].w;
            }
        }
    }

    // ---- epilogue: per-wave shuffle reduction, one atomic per (b, o)
#pragma unroll
    for (int b = 0; b < BATCH; ++b) {
#pragma unroll
        for (int j = 0; j < 4; ++j) {
            float v = acc[b][j];
            v += __shfl_down(v, 32, 64);
            v += __shfl_down(v, 16, 64);
            v += __shfl_down(v, 8, 64);
            v += __shfl_down(v, 4, 64);
            v += __shfl_down(v, 2, 64);
            v += __shfl_down(v, 1, 64);
            if (lane == 0) atomicAdd(out + b * COUT_ + obase + j, v);
        }
    }
}

extern "C" void kernel_launch(void* const* d_in, const int* in_sizes, int n_in,
                              void* d_out, int out_size, void* d_ws, size_t ws_size,
                              hipStream_t stream) {
    const float* x    = (const float*)d_in[0];   // [16,128,4096]
    const float* wgt  = (const float*)d_in[1];   // [128,128,4096]
    const float* bias = (const float*)d_in[2];   // [128]
    float* out = (float*)d_out;                  // [16,128,1]
    (void)in_sizes; (void)n_in; (void)d_ws; (void)ws_size; (void)out_size;

    init_out_kernel<<<8, 256, 0, stream>>>(bias, out);
    conv_dot_kernel<<<4096, 256, 0, stream>>>(x, wgt, out);
}

// Round 6
// 939.562 us; speedup vs baseline: 1.1957x; 1.1957x over previous
//
#include <hip/hip_runtime.h>

// Conv1dFFTInt8: B=16, CIN=128, COUT=128, L=4096, out_size==1.
// Identity: ifft(sum_l X[l]W[l])[0] = sum_n x[n] * w[(L-n) mod L]  (real inputs)
// => out[b,o] = bias[o] + sum_i sum_m w[o,i,m] * x[b,i,(L-m)&(L-1)]
//
// R6: og-loop structure. Grid 512 = ci(128) x kr(4), 2 blocks/CU, one round.
//  - x: reversed-staged into LDS ONCE per block (one barrier in the kernel);
//    x HBM traffic = 32 MB total (read exactly once). All x reads after that
//    are ds_read_b128 on lgkmcnt -> never touch the weight vmcnt chain.
//  - weight: the only vmcnt stream; 2-slot x 4-float4 ring (32 VGPRs) with
//    1-step lookahead that crosses og boundaries and overlaps the epilogue.
//    4 KB/wave in flight x 8 waves/CU = 32 KB/CU >> ~9 KB needed for 6.3 TB/s.
//  - registers: peak live = acc 64 + ring 32 + ptrs/temps ~30 -> ~130, the
//    regime (256,2) handled spill-free in R4. R5's wreg[4][4] (64 forced-live)
//    hit ~190 demand -> allocator spilled (VGPR=128, WRITE 344 MB). R2/R3's
//    (256,3) hard cap also spilled. Both traps avoided here.

constexpr int LEN   = 4096;
constexpr int CIN_  = 128;
constexpr int COUT_ = 128;
constexpr int BATCH = 16;
constexpr int KR    = 1024;   // k-range per block (quarter channel)

typedef float f4 __attribute__((ext_vector_type(4)));

__global__ void init_out_kernel(const float* __restrict__ bias, float* __restrict__ out) {
    int t = blockIdx.x * 256 + threadIdx.x;
    if (t < BATCH * COUT_) out[t] = bias[t & (COUT_ - 1)];
}

__global__ __launch_bounds__(256, 2)
void conv_dot_kernel(const float* __restrict__ x, const float* __restrict__ w,
                     float* __restrict__ out) {
    __shared__ float xs[BATCH * KR];   // 64 KB: xs[b][t] = x[b,ci,(4096-kbase-t)&4095]

    const int tid   = threadIdx.x;
    const int lane  = tid & 63;
    const int wv    = tid >> 6;
    const int bk    = blockIdx.x;      // 0..511
    const int ci    = bk >> 2;         // 0..127
    const int kbase = (bk & 3) << 10;  // 0,1024,2048,3072

    // weight pointers for og=0: couts {wv*4+j}, lane offset folded in
    const float* wp[4];
#pragma unroll
    for (int j = 0; j < 4; ++j)
        wp[j] = w + (((wv * 4 + j) * CIN_ + ci) << 12) + kbase + (lane << 2);
    const long long OGS = (long long)16 * CIN_ * LEN;   // +16 cout rows per og

    f4 ws[2][4];   // 2-slot ring; slot = it&1
    // issue (og0,it0) weight loads BEFORE staging: latency overlaps x staging
#pragma unroll
    for (int j = 0; j < 4; ++j) ws[0][j] = *(const f4*)wp[j];

    // ---- stage reversed x once (coalesced: consecutive tid -> descending n)
    {
        const int  n0   = 4093 - kbase - (tid << 2);
        const bool wrap = (kbase == 0) && (tid == 0);   // k=0 -> n=0 wrap
        const float* xc = x + (ci << 12);
#pragma unroll
        for (int b = 0; b < BATCH; ++b) {
            const float* xb = xc + (b << 19);   // + b * CIN*LEN
            f4 v;
            if (wrap) { v[0] = xb[4093]; v[1] = xb[4094]; v[2] = xb[4095]; v[3] = xb[0]; }
            else       v = *(const f4*)(xb + n0);
            f4 r; r[0] = v[3]; r[1] = v[2]; r[2] = v[1]; r[3] = v[0];  // reverse
            *(f4*)(xs + (b << 10) + (tid << 2)) = r;
        }
    }
    __syncthreads();   // the ONLY barrier

    float acc[BATCH][4];
#pragma unroll
    for (int b = 0; b < BATCH; ++b)
#pragma unroll
        for (int j = 0; j < 4; ++j) acc[b][j] = 0.f;

    for (int og = 0; og < 8; ++og) {
#pragma unroll
        for (int it = 0; it < 4; ++it) {
            const int cur = it & 1, nxt = cur ^ 1;
            if (it < 3) {            // 1-step lookahead within og
#pragma unroll
                for (int j = 0; j < 4; ++j)
                    ws[nxt][j] = *(const f4*)(wp[j] + ((it + 1) << 8));
            } else if (og < 7) {     // lookahead into next og (rides over epilogue)
#pragma unroll
                for (int j = 0; j < 4; ++j)
                    ws[nxt][j] = *(const f4*)(wp[j] + OGS);
            }
            const float* xit = xs + (it << 8) + (lane << 2);
#pragma unroll
            for (int b = 0; b < BATCH; ++b) {
                const f4 xv = *(const f4*)(xit + (b << 10));   // ds_read_b128, 0-conflict
#pragma unroll
                for (int j = 0; j < 4; ++j) {
                    acc[b][j] += xv[0] * ws[cur][j][0];
                    acc[b][j] += xv[1] * ws[cur][j][1];
                    acc[b][j] += xv[2] * ws[cur][j][2];
                    acc[b][j] += xv[3] * ws[cur][j][3];
                }
            }
        }
        // ---- per-og epilogue: 64-lane shuffle reduce (lgkmcnt only -> the
        // next-og weight loads stay in flight underneath), 1 atomic per (b,j)
        const int obase = og * 16 + wv * 4;
#pragma unroll
        for (int b = 0; b < BATCH; ++b) {
#pragma unroll
            for (int j = 0; j < 4; ++j) {
                float v = acc[b][j];
                v += __shfl_down(v, 32, 64);
                v += __shfl_down(v, 16, 64);
                v += __shfl_down(v, 8, 64);
                v += __shfl_down(v, 4, 64);
                v += __shfl_down(v, 2, 64);
                v += __shfl_down(v, 1, 64);
                if (lane == 0) atomicAdd(out + b * COUT_ + obase + j, v);
                acc[b][j] = 0.f;
            }
        }
#pragma unroll
        for (int j = 0; j < 4; ++j) wp[j] += OGS;
    }
}

extern "C" void kernel_launch(void* const* d_in, const int* in_sizes, int n_in,
                              void* d_out, int out_size, void* d_ws, size_t ws_size,
                              hipStream_t stream) {
    const float* x    = (const float*)d_in[0];   // [16,128,4096]
    const float* wgt  = (const float*)d_in[1];   // [128,128,4096]
    const float* bias = (const float*)d_in[2];   // [128]
    float* out = (float*)d_out;                  // [16,128,1]
    (void)in_sizes; (void)n_in; (void)d_ws; (void)ws_size; (void)out_size;

    init_out_kernel<<<8, 256, 0, stream>>>(bias, out);
    conv_dot_kernel<<<512, 256, 0, stream>>>(x, wgt, out);
}